// Round 1
// baseline (69.521 us; speedup 1.0000x reference)
//
#include <hip/hip_runtime.h>
#include <stdint.h>

constexpr int FEAT  = 512;     // feature dim (K)
constexpr int EMB   = 256;     // embed dim   (M)
constexpr int BATCH = 16384;   // batch       (N)
constexpr int NSAMP = 10;
constexpr float SLOPE  = 11.0f / 48.0f;   // RReLU eval slope (1/8+1/3)/2
constexpr float INV_NS = 1.0f / 10.0f;

using f32x4  = __attribute__((ext_vector_type(4))) float;
using frag8  = __attribute__((ext_vector_type(8))) short;  // 8 bf16 (4 VGPRs)

static __device__ __forceinline__ ushort f2b(float x) {
    // round-to-nearest-even f32 -> bf16 (inputs are finite normals)
    unsigned u = __builtin_bit_cast(unsigned, x);
    unsigned r = (u + 0x7fffu + ((u >> 16) & 1u)) >> 16;
    return (ushort)r;
}

// ---------------- kernel 1: gather + mean -> bf16 agg [BATCH][FEAT] ----------
__global__ __launch_bounds__(256) void agg_kernel(const float* __restrict__ feat,
                                                  const int*   __restrict__ idx,
                                                  ushort*      __restrict__ aggb) {
    int t = blockIdx.x * 256 + threadIdx.x;   // BATCH*FEAT/4 threads
    int b = t >> 7;                           // 128 float4 per row
    int c = (t & 127) << 2;                   // float index within row
    const int* ib = idx + b * NSAMP;
    float sx = 0.f, sy = 0.f, sz = 0.f, sw = 0.f;
#pragma unroll
    for (int j = 0; j < NSAMP; ++j) {
        long n = ib[j];
        const float4 v = *reinterpret_cast<const float4*>(feat + n * FEAT + c);
        sx += v.x; sy += v.y; sz += v.z; sw += v.w;
    }
    ushort4 o;
    o.x = f2b(sx * INV_NS); o.y = f2b(sy * INV_NS);
    o.z = f2b(sz * INV_NS); o.w = f2b(sw * INV_NS);
    *reinterpret_cast<ushort4*>(aggb + (size_t)b * FEAT + c) = o;
}

// ---------------- kernel 2: weight f32 -> bf16 ------------------------------
__global__ __launch_bounds__(256) void w2b_kernel(const float* __restrict__ w,
                                                  ushort*      __restrict__ wb) {
    int t = blockIdx.x * 256 + threadIdx.x;   // EMB*FEAT/4 threads
    const float4 v = *reinterpret_cast<const float4*>(w + (size_t)t * 4);
    ushort4 o;
    o.x = f2b(v.x); o.y = f2b(v.y); o.z = f2b(v.z); o.w = f2b(v.w);
    *reinterpret_cast<ushort4*>(wb + (size_t)t * 4) = o;
}

// ---------------- kernel 3: MFMA GEMM: out[e][b] = W[e,:] . Agg[b,:] --------
// A = Wb [EMB][FEAT] bf16, B = Aggb [BATCH][FEAT] bf16 (both K-major = "B^T")
// C = out [EMB][BATCH] f32, fused RReLU.
__global__ __launch_bounds__(256) void gemm_kernel(const ushort* __restrict__ Wb,
                                                   const ushort* __restrict__ Ab,
                                                   float*        __restrict__ out) {
    __shared__ ushort As[128 * 32];   // 8 KB, [row][k] row-major (64 B rows)
    __shared__ ushort Bs[128 * 32];   // 8 KB

    const int tid  = threadIdx.x;
    const int m0   = blockIdx.y * 128;          // over EMB (2 tiles)
    const int n0   = blockIdx.x * 128;          // over BATCH (128 tiles)
    const int w    = tid >> 6;
    const int lane = tid & 63;
    const int wr   = w >> 1, wc = w & 1;        // 2x2 waves, 64x64 each
    const int l15  = lane & 15, lq = lane >> 4;

    f32x4 acc[4][4] = {};

    for (int k0 = 0; k0 < FEAT; k0 += 32) {
#pragma unroll
        for (int cc = 0; cc < 2; ++cc) {
            int o  = cc * 4096 + tid * 16;      // byte offset in tile
            int r  = o >> 6;                    // tile row
            int kk = (o & 63) >> 1;             // bf16 col within row
            __builtin_amdgcn_global_load_lds(
                (const __attribute__((address_space(1))) void*)(Wb + (size_t)(m0 + r) * FEAT + k0 + kk),
                (__attribute__((address_space(3))) void*)((char*)As + o), 16, 0, 0);
            __builtin_amdgcn_global_load_lds(
                (const __attribute__((address_space(1))) void*)(Ab + (size_t)(n0 + r) * FEAT + k0 + kk),
                (__attribute__((address_space(3))) void*)((char*)Bs + o), 16, 0, 0);
        }
        __syncthreads();   // compiler drains vmcnt before s_barrier

        frag8 af[4], bf[4];
#pragma unroll
        for (int i = 0; i < 4; ++i)
            af[i] = *reinterpret_cast<const frag8*>(&As[(wr * 64 + i * 16 + l15) * 32 + lq * 8]);
#pragma unroll
        for (int j = 0; j < 4; ++j)
            bf[j] = *reinterpret_cast<const frag8*>(&Bs[(wc * 64 + j * 16 + l15) * 32 + lq * 8]);

#pragma unroll
        for (int i = 0; i < 4; ++i)
#pragma unroll
            for (int j = 0; j < 4; ++j)
                acc[i][j] = __builtin_amdgcn_mfma_f32_16x16x32_bf16(af[i], bf[j], acc[i][j], 0, 0, 0);
        __syncthreads();
    }

    // epilogue: C/D layout col=lane&15, row=(lane>>4)*4+q  (verified mapping)
#pragma unroll
    for (int i = 0; i < 4; ++i) {
        int row_base = m0 + wr * 64 + i * 16 + lq * 4;
#pragma unroll
        for (int j = 0; j < 4; ++j) {
            int col = n0 + wc * 64 + j * 16 + l15;
#pragma unroll
            for (int q = 0; q < 4; ++q) {
                float y = acc[i][j][q];
                y = (y >= 0.f) ? y : y * SLOPE;
                out[(size_t)(row_base + q) * BATCH + col] = y;
            }
        }
    }
}

// ---------------- fallback (ws too small): fused, slow but correct ----------
__global__ __launch_bounds__(256) void fused_fallback(const float* __restrict__ feat,
                                                      const float* __restrict__ w,
                                                      const int*   __restrict__ idx,
                                                      float*       __restrict__ out) {
    __shared__ float agg[FEAT];
    int b = blockIdx.x;
    const int* ib = idx + b * NSAMP;
    for (int c = threadIdx.x; c < FEAT; c += 256) {
        float s = 0.f;
        for (int j = 0; j < NSAMP; ++j) s += feat[(long)ib[j] * FEAT + c];
        agg[c] = s * INV_NS;
    }
    __syncthreads();
    int e = threadIdx.x;  // EMB == 256 == blockDim
    float a = 0.f;
    const float* wr = w + (size_t)e * FEAT;
    for (int f = 0; f < FEAT; ++f) a += wr[f] * agg[f];
    out[(size_t)e * BATCH + b] = (a >= 0.f) ? a : a * SLOPE;
}

extern "C" void kernel_launch(void* const* d_in, const int* in_sizes, int n_in,
                              void* d_out, int out_size, void* d_ws, size_t ws_size,
                              hipStream_t stream) {
    const float* feat = (const float*)d_in[0];
    const float* wgt  = (const float*)d_in[1];
    const int*   idx  = (const int*)d_in[2];
    float*       out  = (float*)d_out;

    const size_t agg_elems = (size_t)BATCH * FEAT;
    const size_t w_elems   = (size_t)EMB * FEAT;
    const size_t need      = (agg_elems + w_elems) * sizeof(ushort);

    if (ws_size >= need) {
        ushort* aggb = (ushort*)d_ws;
        ushort* wb   = aggb + agg_elems;
        agg_kernel<<<(BATCH * FEAT / 4) / 256, 256, 0, stream>>>(feat, idx, aggb);
        w2b_kernel<<<(EMB * FEAT / 4) / 256, 256, 0, stream>>>(wgt, wb);
        dim3 grid(BATCH / 128, EMB / 128);
        gemm_kernel<<<grid, 256, 0, stream>>>(wb, aggb, out);
    } else {
        fused_fallback<<<BATCH, 256, 0, stream>>>(feat, wgt, idx, out);
    }
}